// Round 1
// baseline (138.696 us; speedup 1.0000x reference)
//
#include <hip/hip_runtime.h>

// SobelLoss: mean over 3 directions of mean |sobel(moved) - sobel(label)|.
// Linearity: conv(m) - conv(l) = conv(m - l). Separable sobel:
//   sx = s(D) x s(H) x d(W), sy = s(D) x d(H) x s(W), sz = -d(D) x s(H) x s(W)
// with s=[1,2,1], d=[-1,0,1]. One pass, rolling 3-plane register window over D,
// single LDS plane (double buffered). Memory-bound: 78.6 MB read, scalar out.

#define BB 2
#define DD 160
#define HH 192
#define WW 160

#define TH 8          // H rows per block
#define DC 10         // D slices per block
#define PSTRIDE 162   // WW + 2 (halo)
#define PROWS   (TH + 2)
#define PELEMS  (PROWS * PSTRIDE)   // 1620
#define NTHREADS 256
#define WPT 5         // outputs per thread along W (32 groups * 5 = 160)

__global__ __launch_bounds__(NTHREADS) void sobel_loss_kernel(
    const float* __restrict__ moved, const float* __restrict__ label,
    float* __restrict__ out)
{
    __shared__ float plane[2][PELEMS];
    __shared__ float red[NTHREADS / 64];

    const int tid = threadIdx.x;
    const int h0  = blockIdx.x * TH;   // 24 tiles: 192/8
    const int d0  = blockIdx.y * DC;   // 16 chunks: 160/10
    const int b   = blockIdx.z;        // 2

    const int base_b = b * (DD * HH * WW);   // fits in int32 (max ~9.8M)

    // compute mapping: 8 h-rows x 32 w-groups of 5
    const int hl    = tid >> 5;        // 0..7
    const int wg    = tid & 31;        // 0..31
    const int wbase = wg * WPT;        // 0..155

    float pxm1[WPT], pxm2[WPT], pym1[WPT], pym2[WPT], pzm1[WPT], pzm2[WPT];
#pragma unroll
    for (int k = 0; k < WPT; ++k) {
        pxm1[k] = pxm2[k] = 0.f;
        pym1[k] = pym2[k] = 0.f;
        pzm1[k] = pzm2[k] = 0.f;
    }

    float acc = 0.f;

    for (int it = 0; it < DC + 2; ++it) {
        const int p = d0 - 1 + it;                 // plane index, may be -1 / DD
        float* buf = plane[it & 1];
        const bool pin = (p >= 0) && (p < DD);

        // ---- stage plane p of (moved - label) into LDS, zero-padded halo ----
        const int pbase = base_b + p * (HH * WW);
        for (int idx = tid; idx < PELEMS; idx += NTHREADS) {
            const int r  = idx / PSTRIDE;          // magic-mul, const divisor
            const int c  = idx - r * PSTRIDE;
            const int gh = h0 + r - 1;
            const int gw = c - 1;
            float v = 0.f;
            if (pin && (unsigned)gh < (unsigned)HH && (unsigned)gw < (unsigned)WW) {
                const int off = pbase + gh * WW + gw;
                v = moved[off] - label[off];
            }
            buf[idx] = v;
        }
        __syncthreads();
        // single sync/iter is safe: before a thread stores into buf[(it+2)&1]
        // it must pass sync of iter it+1, which happens-after all compute of it.

        // ---- per-plane separable partials ----
        const float* r0 = buf + hl * PSTRIDE + wbase;   // global h-1 row
        const float* r1 = r0 + PSTRIDE;                 // h
        const float* r2 = r1 + PSTRIDE;                 // h+1
        float cS[WPT + 2], cD[WPT + 2];
#pragma unroll
        for (int x = 0; x < WPT + 2; ++x) {
            const float a = r0[x], m = r1[x], c2 = r2[x];
            cS[x] = (a + c2) + 2.f * m;   // smooth over H
            cD[x] = c2 - a;               // deriv  over H
        }
#pragma unroll
        for (int k = 0; k < WPT; ++k) {
            const float px = cS[k + 2] - cS[k];                    // dW sH
            const float pz = (cS[k] + cS[k + 2]) + 2.f * cS[k + 1]; // sW sH
            const float py = (cD[k] + cD[k + 2]) + 2.f * cD[k + 1]; // sW dH
            if (it >= 2) {
                const float gx = pxm2[k] + 2.f * pxm1[k] + px;  // smooth D
                const float gy = pym2[k] + 2.f * pym1[k] + py;  // smooth D
                const float gz = pzm2[k] - pz;                  // deriv D: (d-1)-(d+1)
                acc += fabsf(gx) + fabsf(gy) + fabsf(gz);
            }
            pxm2[k] = pxm1[k]; pxm1[k] = px;
            pym2[k] = pym1[k]; pym1[k] = py;
            pzm2[k] = pzm1[k]; pzm1[k] = pz;
        }
    }

    // ---- reduce: wave shuffle -> LDS -> one atomic per block ----
#pragma unroll
    for (int off = 32; off > 0; off >>= 1)
        acc += __shfl_down(acc, off, 64);
    if ((tid & 63) == 0) red[tid >> 6] = acc;
    __syncthreads();
    if (tid == 0) {
        const float s = red[0] + red[1] + red[2] + red[3];
        // final = sum(|gx|+|gy|+|gz|) / (3 * B*D*H*W)
        atomicAdd(out, s * (1.0f / (3.0f * BB * DD * HH * WW)));
    }
}

extern "C" void kernel_launch(void* const* d_in, const int* in_sizes, int n_in,
                              void* d_out, int out_size, void* d_ws, size_t ws_size,
                              hipStream_t stream) {
    const float* moved = (const float*)d_in[0];
    const float* label = (const float*)d_in[1];
    float* out = (float*)d_out;
    (void)in_sizes; (void)n_in; (void)out_size; (void)d_ws; (void)ws_size;

    hipMemsetAsync(out, 0, sizeof(float), stream);   // capture-safe memset node
    dim3 grid(HH / TH, DD / DC, BB);                 // 24 x 16 x 2 = 768 blocks
    sobel_loss_kernel<<<grid, NTHREADS, 0, stream>>>(moved, label, out);
}